// Round 12
// baseline (280.668 us; speedup 1.0000x reference)
//
#include <hip/hip_runtime.h>
#include <hip/hip_bf16.h>
#include <hip/hip_fp16.h>
#include <math.h>

// ---------------------------------------------------------------------------
// GATv2 policy net: 2x GATv2 layer (H=2, C=32, share_weights) + edge MLP.
// CSR build = bucketed counting sort (128 nodes/bucket), LDS counting.
// Layer 0: rank-2 decomposition (x is 2-dim):
//   wgt0 (edge-parallel) -> wrec{w0,w1,xs.x,xs.y}; hagg0 (lanes=edges,
//   6-scalar butterfly) + rank-2 epilogue. No serial per-edge chain.
// Layer 1: fused attention+aggregation (ILP-8, lane=channel); z1 stored FP16.
// Cross-lane reduces ride the idle DS pipe (ds_swizzle xor hops): 1 v_add +
// 1 DS op per hop vs DPP's potential 3-VALU lowering; ILP-8 hides DS latency.
// Unnormalized softmax (clamp 60): exp cannot overflow; same math.
// Fusions: init+bfrag (setup); easum+bhist (pre); gvec inside 2nd gemm.
// ---------------------------------------------------------------------------

typedef __attribute__((ext_vector_type(8))) short short8;
typedef __attribute__((ext_vector_type(4))) float f32x4;

#define BSH 7               // 128 nodes per bucket
#define CH 4096             // edges per block in pre/phaseA

template <int IMM>
__device__ __forceinline__ float swz(float x) {
    return __int_as_float(__builtin_amdgcn_ds_swizzle(__float_as_int(x), IMM));
}

template <int CTRL>
__device__ __forceinline__ float dpp_add(float p) {
    int t = __builtin_amdgcn_update_dpp(0, __float_as_int(p), CTRL, 0xF, 0xF, true);
    return p + __int_as_float(t);
}

// sum over the 32 lanes of this head; result in all lanes. DS-pipe hops.
__device__ __forceinline__ float head_reduce(float p) {
    p += swz<0x041F>(p);      // xor 1
    p += swz<0x081F>(p);      // xor 2
    p += swz<0x101F>(p);      // xor 4
    p += swz<0x201F>(p);      // xor 8
    p += swz<0x401F>(p);      // xor 16
    return p;
}

// truncating fp32 -> (hi, lo) bf16 split
__device__ __forceinline__ short2 bsplit(float x) {
    unsigned u = __float_as_uint(x);
    short hi = (short)(u >> 16);
    float hif = __uint_as_float(u & 0xFFFF0000u);
    short lo = (short)(__float_as_uint(x - hif) >> 16);
    return make_short2(hi, lo);
}

// ---- setup: blocks 0,1 = bfrag (split-bf16 B fragments); block 2 = zeroing --
__global__ __launch_bounds__(512) void setup_kernel(const float* __restrict__ W1,
                                                    const float* __restrict__ Wm1,
                                                    short* __restrict__ BfW1,
                                                    short* __restrict__ BfWm,
                                                    int* __restrict__ bucket_base,
                                                    float* __restrict__ easum, int nbuck) {
    if (blockIdx.x == 2) {
        for (int i = threadIdx.x; i <= nbuck; i += 512) bucket_base[i] = 0;
        if (threadIdx.x < 2) easum[threadIdx.x] = 0.f;
        return;
    }
    int snt = threadIdx.x >> 6;
    int lane = threadIdx.x & 63;
    int s = snt >> 2, nt = snt & 3;
    int col = nt * 16 + (lane & 15);
    short* Bf = blockIdx.x == 0 ? BfW1 : BfWm;
#pragma unroll
    for (int j = 0; j < 8; ++j) {
        int k = s * 32 + (lane >> 4) * 8 + j;
        float v;
        if (blockIdx.x == 0) {
            v = W1[k * 64 + col];
        } else {
            v = (col < 32) ? Wm1[k * 32 + col] : Wm1[(64 + k) * 32 + (col - 32)];
        }
        short2 t = bsplit(v);
        Bf[(snt * 2 + 0) * 512 + lane * 8 + j] = t.x;
        Bf[(snt * 2 + 1) * 512 + lane * 8 + j] = t.y;
    }
}

// ---- pre: easum (block-tree + 2 atomics/block) fused with bucket histogram --
__global__ __launch_bounds__(256) void pre_kernel(const int* __restrict__ ei,
                                                  const float2* __restrict__ ea,
                                                  int* __restrict__ bucket_base,
                                                  float* __restrict__ easum,
                                                  int E, int EP, int nbuck) {
    extern __shared__ int lcnt[];
    __shared__ float r0[4], r1[4];
    int tid = threadIdx.x;
    for (int i = tid; i < nbuck; i += 256) lcnt[i] = 0;
    float s0 = 0.f, s1 = 0.f;
    int estride = gridDim.x * 256;
    for (int e = blockIdx.x * 256 + tid; e < E; e += estride) {
        float2 v = ea[e];
        s0 += v.x; s1 += v.y;
    }
#pragma unroll
    for (int o = 32; o >= 1; o >>= 1) {
        s0 += __shfl_xor(s0, o);
        s1 += __shfl_xor(s1, o);
    }
    int wave = tid >> 6;
    if ((tid & 63) == 0) { r0[wave] = s0; r1[wave] = s1; }
    __syncthreads();
    int base = blockIdx.x * CH;
    int end = min(base + CH, EP);
    for (int i = base + tid; i < end; i += 256) {
        int d = (i < E) ? ei[E + i] : (i - E);
        atomicAdd(&lcnt[d >> BSH], 1);
    }
    __syncthreads();
    if (tid == 0) {
        atomicAdd(&easum[0], r0[0] + r0[1] + r0[2] + r0[3]);
        atomicAdd(&easum[1], r1[0] + r1[1] + r1[2] + r1[3]);
    }
    for (int i = tid; i < nbuck; i += 256) {
        int c = lcnt[i];
        if (c) atomicAdd(&bucket_base[i], c);
    }
}

// single-block exclusive scan of bucket counts
__global__ __launch_bounds__(256) void bscan_kernel(int* __restrict__ bucket_base,
                                                    int* __restrict__ bucket_cursor,
                                                    int* __restrict__ row_ptr,
                                                    int N, int nbuck) {
    __shared__ int sm[256];
    int tid = threadIdx.x;
    int K = (nbuck + 255) / 256;
    int b0 = tid * K;
    int local = 0;
    for (int k = 0; k < K; ++k) {
        int b = b0 + k;
        if (b < nbuck) local += bucket_base[b];
    }
    sm[tid] = local;
    __syncthreads();
    for (int st = 1; st < 256; st <<= 1) {
        int v = sm[tid];
        int a = (tid >= st) ? sm[tid - st] : 0;
        __syncthreads();
        sm[tid] = v + a;
        __syncthreads();
    }
    int run = (tid == 0) ? 0 : sm[tid - 1];
    for (int k = 0; k < K; ++k) {
        int b = b0 + k;
        if (b < nbuck) {
            int c = bucket_base[b];
            bucket_base[b] = run;
            bucket_cursor[b] = run;
            run += c;
        }
    }
    if (tid == 255) {
        bucket_base[nbuck] = sm[255];
        row_ptr[N] = sm[255];
    }
}

// partition edges into bucket-contiguous staged[]; records {src, eax, eay, dst}
__global__ __launch_bounds__(256) void phaseA_kernel(const int* __restrict__ ei,
                                                     const float2* __restrict__ ea,
                                                     const float* __restrict__ easum,
                                                     int* __restrict__ bucket_cursor,
                                                     float4* __restrict__ staged,
                                                     int E, int EP, int nbuck) {
    extern __shared__ int sm[];          // lcnt[nbuck] then lbase[nbuck]
    int* lcnt = sm;
    int* lbase = sm + nbuck;
    int tid = threadIdx.x;
    for (int i = tid; i < nbuck; i += 256) lcnt[i] = 0;
    __syncthreads();
    int base = blockIdx.x * CH;
    int end = min(base + CH, EP);
    for (int i = base + tid; i < end; i += 256) {
        int d = (i < E) ? ei[E + i] : (i - E);
        atomicAdd(&lcnt[d >> BSH], 1);
    }
    __syncthreads();
    for (int i = tid; i < nbuck; i += 256) {
        int c = lcnt[i];
        lbase[i] = c ? atomicAdd(&bucket_cursor[i], c) : 0;
        lcnt[i] = 0;
    }
    __syncthreads();
    float inv = 1.f / (float)E;
    float m0 = easum[0] * inv, m1 = easum[1] * inv;
    for (int i = base + tid; i < end; i += 256) {
        int s, d; float ex, ey;
        if (i < E) {
            s = ei[i]; d = ei[E + i];
            float2 v = ea[i]; ex = v.x; ey = v.y;
        } else {
            s = d = i - E; ex = m0; ey = m1;
        }
        int b = d >> BSH;
        int pos = lbase[b] + atomicAdd(&lcnt[b], 1);
        staged[pos] = make_float4(__int_as_float(s), ex, ey, __int_as_float(d));
    }
}

// per bucket: per-node LDS count + scan -> row_ptr; exact CSR placement
__global__ __launch_bounds__(256) void phaseB_kernel(const float4* __restrict__ staged,
                                                     const int* __restrict__ bucket_base,
                                                     int* __restrict__ row_ptr,
                                                     float4* __restrict__ recs, int N) {
    __shared__ int cnt128[128];
    __shared__ int offs[128];
    int b = blockIdx.x;
    int n0 = b << BSH;
    int tid = threadIdx.x;
    if (tid < 128) cnt128[tid] = 0;
    __syncthreads();
    int begs = bucket_base[b];
    int ends = bucket_base[b + 1];
    for (int i = begs + tid; i < ends; i += 256) {
        int d = __float_as_int(staged[i].w);
        atomicAdd(&cnt128[d - n0], 1);
    }
    __syncthreads();
    if (tid < 128) offs[tid] = cnt128[tid];
    __syncthreads();
    for (int st = 1; st < 128; st <<= 1) {
        int v = 0;
        if (tid < 128) {
            v = offs[tid];
            if (tid >= st) v += offs[tid - st];
        }
        __syncthreads();
        if (tid < 128) offs[tid] = v;
        __syncthreads();
    }
    if (tid < 128) {
        int excl = begs + offs[tid] - cnt128[tid];
        int node = n0 + tid;
        if (node < N) row_ptr[node] = excl;
        offs[tid] = excl;
    }
    __syncthreads();
    for (int i = begs + tid; i < ends; i += 256) {
        float4 r = staged[i];
        int d = __float_as_int(r.w);
        int pos = atomicAdd(&offs[d - n0], 1);
        recs[pos] = r;
    }
}

// ---- wgt0: edge-parallel layer-0 attention weights --------------------------
__global__ __launch_bounds__(256) void wgt0_kernel(const float2* __restrict__ x,
                                                   const float* __restrict__ W0,
                                                   const float* __restrict__ b0,
                                                   const float4* __restrict__ recs,
                                                   const float* __restrict__ We,
                                                   const float* __restrict__ att,
                                                   float4* __restrict__ wrec, int EP) {
    int lane = threadIdx.x & 63;
    int m = lane & 15, quad = lane >> 4;
    int c0 = quad * 8, c1 = 32 + c0;
    float w0a[8], w1a[8], ata[8], w0b[8], w1b[8], atb[8];
    float Wxa[8], Wya[8], bca[8], Wxb[8], Wyb[8], bcb[8];
#pragma unroll
    for (int j = 0; j < 8; ++j) {
        w0a[j] = We[c0 + j];  w1a[j] = We[64 + c0 + j];  ata[j] = att[c0 + j];
        w0b[j] = We[c1 + j];  w1b[j] = We[64 + c1 + j];  atb[j] = att[c1 + j];
        Wxa[j] = W0[c0 + j];  Wya[j] = W0[64 + c0 + j];  bca[j] = b0[c0 + j];
        Wxb[j] = W0[c1 + j];  Wyb[j] = W0[64 + c1 + j];  bcb[j] = b0[c1 + j];
    }
    int ntiles = (EP + 15) >> 4;
    int wid = (blockIdx.x * blockDim.x + threadIdx.x) >> 6;
    int nw = (gridDim.x * blockDim.x) >> 6;
    for (int t = wid; t < ntiles; t += nw) {
        int e = t * 16 + m;
        int ec = e < EP ? e : EP - 1;
        float4 r = recs[ec];
        int s = __float_as_int(r.x);
        int d = __float_as_int(r.w);
        float2 xs = x[s];
        float2 xd = x[d];
        float P0 = 0.f, P1 = 0.f;
#pragma unroll
        for (int j = 0; j < 8; ++j) {
            float zs = fmaf(xs.x, Wxa[j], fmaf(xs.y, Wya[j], bca[j]));
            float zd = fmaf(xd.x, Wxa[j], fmaf(xd.y, Wya[j], bca[j]));
            float t0 = zd + zs + fmaf(r.y, w0a[j], r.z * w1a[j]);
            t0 = fmaxf(t0, 0.2f * t0);
            P0 = fmaf(t0, ata[j], P0);
            float zs1 = fmaf(xs.x, Wxb[j], fmaf(xs.y, Wyb[j], bcb[j]));
            float zd1 = fmaf(xd.x, Wxb[j], fmaf(xd.y, Wyb[j], bcb[j]));
            float t1 = zd1 + zs1 + fmaf(r.y, w0b[j], r.z * w1b[j]);
            t1 = fmaxf(t1, 0.2f * t1);
            P1 = fmaf(t1, atb[j], P1);
        }
        P0 += swz<0x401F>(P0);             // quad pair (xor 16)
        P1 += swz<0x401F>(P1);
        P0 += __shfl_xor(P0, 32);          // cross-half (xor 32)
        P1 += __shfl_xor(P1, 32);
        float w0 = __expf(fminf(P0, 60.f));
        float w1 = __expf(fminf(P1, 60.f));
        if (lane < 16 && e < EP) wrec[e] = make_float4(w0, w1, xs.x, xs.y);
    }
}

// ---- hagg0: wave/node, lanes=EDGES; stream wrec; 6-scalar butterfly ---------
__global__ __launch_bounds__(256) void hagg0_kernel(const float4* __restrict__ wrec,
                                                    const int* __restrict__ row_ptr,
                                                    const float* __restrict__ W0,
                                                    const float* __restrict__ b0,
                                                    const float* __restrict__ bias,
                                                    float* __restrict__ hout, int N) {
    int gtid = blockIdx.x * blockDim.x + threadIdx.x;
    int n = gtid >> 6;
    if (n >= N) return;
    n = __builtin_amdgcn_readfirstlane(n);
    int lane = threadIdx.x & 63;
    int beg = row_ptr[n], end = row_ptr[n + 1];
    float a0 = 0.f, a1 = 0.f, a2 = 0.f, c0 = 0.f, c1 = 0.f, c2 = 0.f;
    for (int i = beg + lane; i < end; i += 64) {
        float4 r = wrec[i];
        a0 += r.x; a1 = fmaf(r.x, r.z, a1); a2 = fmaf(r.x, r.w, a2);
        c0 += r.y; c1 = fmaf(r.y, r.z, c1); c2 = fmaf(r.y, r.w, c2);
    }
#pragma unroll
    for (int o = 32; o >= 1; o >>= 1) {
        a0 += __shfl_xor(a0, o); a1 += __shfl_xor(a1, o); a2 += __shfl_xor(a2, o);
        c0 += __shfl_xor(c0, o); c1 += __shfl_xor(c1, o); c2 += __shfl_xor(c2, o);
    }
    int head = lane >> 5;
    float l  = head ? c0 : a0;
    float Sx = head ? c1 : a1;
    float Sy = head ? c2 : a2;
    float num = fmaf(W0[lane], Sx, fmaf(W0[64 + lane], Sy, b0[lane] * l));
    float v = num / (l + 1e-16f) + bias[lane];
    v = (v > 0.f) ? v : expm1f(v);       // ELU
    hout[(size_t)n * 64 + lane] = v;
}

// ---- agg1: fused attention+aggregation, layer 1; z stored FP16 --------------
__global__ __launch_bounds__(256) void agg1_kernel(
    const __half* __restrict__ z, const int* __restrict__ row_ptr,
    const float4* __restrict__ recs,
    const float* __restrict__ We, const float* __restrict__ att,
    const float* __restrict__ bias, float* __restrict__ hout, int N) {
    int gtid = blockIdx.x * blockDim.x + threadIdx.x;
    int n = gtid >> 6;
    if (n >= N) return;
    n = __builtin_amdgcn_readfirstlane(n);
    int lane = threadIdx.x & 63;

    float We0 = We[lane], We1 = We[64 + lane];
    float attj = att[lane];
    float zn = __half2float(z[(size_t)n * 64 + lane]);

    int beg = row_ptr[n], end = row_ptr[n + 1];
    float ll[4] = {0.f, 0.f, 0.f, 0.f};
    float aa[4] = {0.f, 0.f, 0.f, 0.f};
    int i = beg;
    for (; i + 8 <= end; i += 8) {
        float w[8], zs[8];
#pragma unroll
        for (int k = 0; k < 8; ++k) {
            float4 r = recs[i + k];
            int s = __builtin_amdgcn_readfirstlane(__float_as_int(r.x));
            float zv = __half2float(z[(size_t)s * 64 + lane]);
            float sj = zn + zv + fmaf(r.y, We0, r.z * We1);
            sj = fmaxf(sj, 0.2f * sj);
            float alpha = head_reduce(sj * attj);
            w[k] = __expf(fminf(alpha, 60.f));
            zs[k] = zv;
        }
#pragma unroll
        for (int k = 0; k < 8; ++k) {
            ll[k & 3] += w[k];
            aa[k & 3] = fmaf(w[k], zs[k], aa[k & 3]);
        }
    }
    for (; i < end; ++i) {
        float4 r = recs[i];
        int s = __builtin_amdgcn_readfirstlane(__float_as_int(r.x));
        float zv = __half2float(z[(size_t)s * 64 + lane]);
        float sj = zn + zv + fmaf(r.y, We0, r.z * We1);
        sj = fmaxf(sj, 0.2f * sj);
        float alpha = head_reduce(sj * attj);
        float w = __expf(fminf(alpha, 60.f));
        ll[0] += w;
        aa[0] = fmaf(w, zv, aa[0]);
    }
    float l = (ll[0] + ll[1]) + (ll[2] + ll[3]);
    float a = (aa[0] + aa[1]) + (aa[2] + aa[3]);
    float v = a / (l + 1e-16f) + bias[lane];
    v = (v > 0.f) ? v : expm1f(v);
    hout[(size_t)n * 64 + lane] = v;
}

// ---- out[N x 64] = h[N x 64] @ B[64 x 64] (+ bias), split-bf16 MFMA ---------
// FP16 output (consumed by random-gather kernels: halves their HBM traffic).
__global__ __launch_bounds__(256) void mfma_gemm64(const float* __restrict__ h,
                                                   const short* __restrict__ Bf,
                                                   const float* __restrict__ bias,
                                                   __half* __restrict__ out, int N,
                                                   const float* __restrict__ Wm1,
                                                   const float* __restrict__ bm1,
                                                   const int* __restrict__ dest,
                                                   float* __restrict__ gv) {
    int wave = threadIdx.x >> 6;
    int lane = threadIdx.x & 63;
    int n0 = blockIdx.x * 64 + wave * 16;
    if (n0 < N) {
        int m = lane & 15, quad = lane >> 4;
        int arow = n0 + m;
        if (arow > N - 1) arow = N - 1;
        f32x4 acc[4] = {{0.f, 0.f, 0.f, 0.f}, {0.f, 0.f, 0.f, 0.f},
                        {0.f, 0.f, 0.f, 0.f}, {0.f, 0.f, 0.f, 0.f}};
#pragma unroll
        for (int s = 0; s < 2; ++s) {
            const float* ap = h + (size_t)arow * 64 + s * 32 + quad * 8;
            float4 a0 = *(const float4*)ap;
            float4 a1 = *(const float4*)(ap + 4);
            short8 ahi, alo;
            short2 t;
            t = bsplit(a0.x); ahi[0] = t.x; alo[0] = t.y;
            t = bsplit(a0.y); ahi[1] = t.x; alo[1] = t.y;
            t = bsplit(a0.z); ahi[2] = t.x; alo[2] = t.y;
            t = bsplit(a0.w); ahi[3] = t.x; alo[3] = t.y;
            t = bsplit(a1.x); ahi[4] = t.x; alo[4] = t.y;
            t = bsplit(a1.y); ahi[5] = t.x; alo[5] = t.y;
            t = bsplit(a1.z); ahi[6] = t.x; alo[6] = t.y;
            t = bsplit(a1.w); ahi[7] = t.x; alo[7] = t.y;
#pragma unroll
            for (int nt = 0; nt < 4; ++nt) {
                const short* bp = Bf + ((s * 4 + nt) * 2) * 512 + lane * 8;
                short8 bhi = *(const short8*)bp;
                short8 blo = *(const short8*)(bp + 512);
                acc[nt] = __builtin_amdgcn_mfma_f32_16x16x32_bf16(ahi, bhi, acc[nt], 0, 0, 0);
                acc[nt] = __builtin_amdgcn_mfma_f32_16x16x32_bf16(ahi, blo, acc[nt], 0, 0, 0);
                acc[nt] = __builtin_amdgcn_mfma_f32_16x16x32_bf16(alo, bhi, acc[nt], 0, 0, 0);
            }
        }
#pragma unroll
        for (int nt = 0; nt < 4; ++nt) {
            int col = nt * 16 + m;
            float bj = bias ? bias[col] : 0.f;
#pragma unroll
            for (int r = 0; r < 4; ++r) {
                int orow = n0 + quad * 4 + r;
                if (orow < N) out[(size_t)orow * 64 + col] = __float2half(acc[nt][r] + bj);
            }
        }
    }
    if (gv && blockIdx.x == 0 && threadIdx.x < 32) {
        int dd = dest[0];
        int q = threadIdx.x;
        float acc2 = bm1[q];
        for (int k = 0; k < 64; ++k)
            acc2 = fmaf(h[(size_t)dd * 64 + k], Wm1[(128 + k) * 32 + q], acc2);
        gv[q] = acc2;
    }
}

// 8 lanes per edge; hsd FP16: [n*64+0:32]=hs, [n*64+32:64]=hd
__global__ __launch_bounds__(256) void edge_mlp_kernel(
    const int* __restrict__ ei, const float2* __restrict__ ea,
    const __half* __restrict__ hsd, const float* __restrict__ gvec,
    const float* __restrict__ WrowA, const float* __restrict__ WrowB,
    const float* __restrict__ Wm2, const float* __restrict__ bm2,
    float* __restrict__ out, int E) {
    int tid = blockIdx.x * blockDim.x + threadIdx.x;
    int e = tid >> 3;
    int j = tid & 7;
    if (e >= E) return;
    int s = ei[e], d = ei[E + e];
    float2 eav = ea[e];
    const __half2* ps = (const __half2*)(hsd + (size_t)s * 64 + j * 4);
    const __half2* pd = (const __half2*)(hsd + (size_t)d * 64 + 32 + j * 4);
    float2 a01 = __half22float2(ps[0]), a23 = __half22float2(ps[1]);
    float2 b01 = __half22float2(pd[0]), b23 = __half22float2(pd[1]);
    float4 g = *(const float4*)(gvec + j * 4);
    float4 wa = *(const float4*)(WrowA + j * 4);
    float4 wb = *(const float4*)(WrowB + j * 4);
    float4 w2 = *(const float4*)(Wm2 + j * 4);
    float acc = 0.f, v;
    v = fmaf(eav.x, wa.x, fmaf(eav.y, wb.x, a01.x + b01.x + g.x)); v = fmaxf(v, 0.f); acc = fmaf(v, w2.x, acc);
    v = fmaf(eav.x, wa.y, fmaf(eav.y, wb.y, a01.y + b01.y + g.y)); v = fmaxf(v, 0.f); acc = fmaf(v, w2.y, acc);
    v = fmaf(eav.x, wa.z, fmaf(eav.y, wb.z, a23.x + b23.x + g.z)); v = fmaxf(v, 0.f); acc = fmaf(v, w2.z, acc);
    v = fmaf(eav.x, wa.w, fmaf(eav.y, wb.w, a23.y + b23.y + g.w)); v = fmaxf(v, 0.f); acc = fmaf(v, w2.w, acc);
    acc += swz<0x041F>(acc);    // xor 1 (DS pipe)
    acc += swz<0x081F>(acc);    // xor 2
    acc += swz<0x101F>(acc);    // xor 4 — closes the 8-group
    if (j == 0) out[e] = acc + bm2[0];
}

extern "C" void kernel_launch(void* const* d_in, const int* in_sizes, int n_in,
                              void* d_out, int out_size, void* d_ws, size_t ws_size,
                              hipStream_t stream) {
    const float* x     = (const float*)d_in[0];
    const int*   ei    = (const int*)d_in[1];
    const float* ea    = (const float*)d_in[2];
    const int*   dest  = (const int*)d_in[3];
    const float* W0    = (const float*)d_in[4];
    const float* b0    = (const float*)d_in[5];
    const float* We0   = (const float*)d_in[6];
    const float* att0  = (const float*)d_in[7];
    const float* bias0 = (const float*)d_in[8];
    const float* W1    = (const float*)d_in[9];
    const float* b1    = (const float*)d_in[10];
    const float* We1   = (const float*)d_in[11];
    const float* att1  = (const float*)d_in[12];
    const float* bias1 = (const float*)d_in[13];
    const float* Wm1   = (const float*)d_in[14];
    const float* bm1   = (const float*)d_in[15];
    const float* Wm2   = (const float*)d_in[16];
    const float* bm2   = (const float*)d_in[17];

    const int N = in_sizes[0] / 2;
    const int E = in_sizes[1] / 2;
    const int EP = E + N;
    const int nbuck = (N + 127) >> BSH;
    const int nchunk = (EP + CH - 1) / CH;

    char* ws = (char*)d_ws;
    size_t off = 0;
    auto alloc = [&](size_t bytes) -> void* {
        void* p = ws + off;
        off += bytes;
        off = (off + 255) & ~(size_t)255;
        return p;
    };
    int*    bucket_base   = (int*)alloc((size_t)(nbuck + 1) * 4);
    int*    bucket_cursor = (int*)alloc((size_t)nbuck * 4);
    int*    row_ptr       = (int*)alloc((size_t)(N + 1) * 4);
    size_t  shared_bytes  = (size_t)EP * 16 > (size_t)N * 128 ? (size_t)EP * 16
                                                              : (size_t)N * 128;
    float4* staged        = (float4*)alloc(shared_bytes);   // also z16/hsd16 (N*64*2B)
    float4* recs          = (float4*)alloc((size_t)EP * 16);
    float4* wrec          = (float4*)alloc((size_t)EP * 16);
    float*  hbuf          = (float*)alloc((size_t)N * 64 * 4);
    float*  easum         = (float*)alloc(8);
    float*  gvec          = (float*)alloc(32 * 4);
    short*  BfW1          = (short*)alloc(8192 * 2);
    short*  BfWm          = (short*)alloc(8192 * 2);
    __half* z16           = (__half*)staged;  // staged dead before gemm writes
    __half* hsd16         = z16;              // z1 dead after layer-1 agg

    dim3 blk(256);
    setup_kernel<<<3, 512, 0, stream>>>(W1, Wm1, BfW1, BfWm, bucket_base, easum, nbuck);
    pre_kernel<<<nchunk, blk, (size_t)nbuck * 4, stream>>>(ei, (const float2*)ea,
                                                           bucket_base, easum, E, EP, nbuck);
    bscan_kernel<<<1, blk, 0, stream>>>(bucket_base, bucket_cursor, row_ptr, N, nbuck);
    phaseA_kernel<<<nchunk, blk, (size_t)nbuck * 8, stream>>>(ei, (const float2*)ea, easum,
                                                              bucket_cursor, staged, E, EP, nbuck);
    phaseB_kernel<<<nbuck, blk, 0, stream>>>(staged, bucket_base, row_ptr, recs, N);
    wgt0_kernel<<<2048, blk, 0, stream>>>((const float2*)x, W0, b0, recs, We0, att0, wrec, EP);
    hagg0_kernel<<<(N * 64 + 255) / 256, blk, 0, stream>>>(wrec, row_ptr, W0, b0,
                                                           bias0, hbuf, N);
    mfma_gemm64<<<(N + 63) / 64, blk, 0, stream>>>(hbuf, BfW1, b1, z16, N,
                                                   nullptr, nullptr, nullptr, nullptr);
    agg1_kernel<<<(N * 64 + 255) / 256, blk, 0, stream>>>(z16, row_ptr, recs,
                                                          We1, att1, bias1, hbuf, N);
    mfma_gemm64<<<(N + 63) / 64, blk, 0, stream>>>(hbuf, BfWm, (const float*)nullptr, hsd16, N,
                                                   Wm1, bm1, dest, gvec);
    edge_mlp_kernel<<<((size_t)E * 8 + 255) / 256, blk, 0, stream>>>(
        ei, (const float2*)ea, hsd16, gvec,
        Wm1 + 192 * 32, Wm1 + 193 * 32, Wm2, bm2, (float*)d_out, E);
}

// Round 13
// 266.061 us; speedup vs baseline: 1.0549x; 1.0549x over previous
//
#include <hip/hip_runtime.h>
#include <hip/hip_bf16.h>
#include <hip/hip_fp16.h>
#include <math.h>

// ---------------------------------------------------------------------------
// GATv2 policy net: 2x GATv2 layer (H=2, C=32, share_weights) + edge MLP.
// CSR build = slack-bucket counting sort (128 nodes/bucket, CAP=4096 slack):
//   phaseA appends E real edges into per-bucket slack runs (LDS count +
//   one cursor atomicAdd per (block,bucket)); easum fused (phaseA reads ea).
//   bscan: slack counts (+1 selfloop/node) -> bucket_base, row_ptr[N].
//   phaseB: per-node count+scan -> row_ptr; synthesizes the selfloop record
//   {n, mean(ea), n} at each node's first CSR slot; places real records.
// Layer 0: rank-2 decomposition (x is 2-dim): wgt0 (edge-parallel) -> wrec;
//   hagg0 (lanes=edges, 6-scalar butterfly) + rank-2 epilogue.
// Layer 1: fused attention+aggregation (ILP-8, lane=channel); z1 FP16.
// Cross-lane reduces use DPP (R12 showed ds_swizzle hops are slower).
// Unnormalized softmax (clamp 60): exp cannot overflow; same math.
// ---------------------------------------------------------------------------

typedef __attribute__((ext_vector_type(8))) short short8;
typedef __attribute__((ext_vector_type(4))) float f32x4;

#define BSH 7               // 128 nodes per bucket
#define CAP 4096            // slack per bucket (mean 2048, sigma ~45)
#define CH 4096             // edges per block in phaseA

template <int IMM>
__device__ __forceinline__ float swz(float x) {
    return __int_as_float(__builtin_amdgcn_ds_swizzle(__float_as_int(x), IMM));
}

template <int CTRL>
__device__ __forceinline__ float dpp_add(float p) {
    int t = __builtin_amdgcn_update_dpp(0, __float_as_int(p), CTRL, 0xF, 0xF, true);
    return p + __int_as_float(t);
}

// sum over the 32 lanes of this head; result in all lanes (DPP + 1 swizzle).
__device__ __forceinline__ float head_reduce(float p) {
    p = dpp_add<0xB1>(p);     // xor 1
    p = dpp_add<0x4E>(p);     // xor 2
    p = dpp_add<0x141>(p);    // xor 7 (half mirror)
    p = dpp_add<0x140>(p);    // xor 15 (row mirror)
    p += swz<0x401F>(p);      // xor 16
    return p;
}

// truncating fp32 -> (hi, lo) bf16 split
__device__ __forceinline__ short2 bsplit(float x) {
    unsigned u = __float_as_uint(x);
    short hi = (short)(u >> 16);
    float hif = __uint_as_float(u & 0xFFFF0000u);
    short lo = (short)(__float_as_uint(x - hif) >> 16);
    return make_short2(hi, lo);
}

// ---- setup: blocks 0,1 = bfrag; block 2 = init cursors + easum --------------
__global__ __launch_bounds__(512) void setup_kernel(const float* __restrict__ W1,
                                                    const float* __restrict__ Wm1,
                                                    short* __restrict__ BfW1,
                                                    short* __restrict__ BfWm,
                                                    int* __restrict__ bucket_cursor,
                                                    float* __restrict__ easum, int nbuck) {
    if (blockIdx.x == 2) {
        for (int i = threadIdx.x; i < nbuck; i += 512) bucket_cursor[i] = i * CAP;
        if (threadIdx.x < 2) easum[threadIdx.x] = 0.f;
        return;
    }
    int snt = threadIdx.x >> 6;
    int lane = threadIdx.x & 63;
    int s = snt >> 2, nt = snt & 3;
    int col = nt * 16 + (lane & 15);
    short* Bf = blockIdx.x == 0 ? BfW1 : BfWm;
#pragma unroll
    for (int j = 0; j < 8; ++j) {
        int k = s * 32 + (lane >> 4) * 8 + j;
        float v;
        if (blockIdx.x == 0) {
            v = W1[k * 64 + col];
        } else {
            v = (col < 32) ? Wm1[k * 32 + col] : Wm1[(64 + k) * 32 + (col - 32)];
        }
        short2 t = bsplit(v);
        Bf[(snt * 2 + 0) * 512 + lane * 8 + j] = t.x;
        Bf[(snt * 2 + 1) * 512 + lane * 8 + j] = t.y;
    }
}

// ---- phaseA: append E edges into slack bucket runs; easum fused -------------
__global__ __launch_bounds__(256) void phaseA_kernel(const int* __restrict__ ei,
                                                     const float2* __restrict__ ea,
                                                     int* __restrict__ bucket_cursor,
                                                     float* __restrict__ easum,
                                                     float4* __restrict__ staged,
                                                     int E, int nbuck) {
    extern __shared__ int sm[];          // lcnt[nbuck] then lbase[nbuck]
    int* lcnt = sm;
    int* lbase = sm + nbuck;
    __shared__ float r0[4], r1[4];
    int tid = threadIdx.x;
    for (int i = tid; i < nbuck; i += 256) lcnt[i] = 0;
    __syncthreads();
    int base = blockIdx.x * CH;
    int end = min(base + CH, E);
    for (int i = base + tid; i < end; i += 256) {
        int d = ei[E + i];
        atomicAdd(&lcnt[d >> BSH], 1);
    }
    __syncthreads();
    for (int i = tid; i < nbuck; i += 256) {
        int c = lcnt[i];
        lbase[i] = c ? atomicAdd(&bucket_cursor[i], c) : 0;
        lcnt[i] = 0;
    }
    __syncthreads();
    float s0 = 0.f, s1 = 0.f;
    for (int i = base + tid; i < end; i += 256) {
        int s = ei[i], d = ei[E + i];
        float2 v = ea[i];
        s0 += v.x; s1 += v.y;
        int b = d >> BSH;
        int pos = lbase[b] + atomicAdd(&lcnt[b], 1);
        staged[pos] = make_float4(__int_as_float(s), v.x, v.y, __int_as_float(d));
    }
#pragma unroll
    for (int o = 32; o >= 1; o >>= 1) {
        s0 += __shfl_xor(s0, o);
        s1 += __shfl_xor(s1, o);
    }
    int wave = tid >> 6;
    if ((tid & 63) == 0) { r0[wave] = s0; r1[wave] = s1; }
    __syncthreads();
    if (tid == 0) {
        atomicAdd(&easum[0], r0[0] + r0[1] + r0[2] + r0[3]);
        atomicAdd(&easum[1], r1[0] + r1[1] + r1[2] + r1[3]);
    }
}

// ---- bscan: slack counts (+selfloops) -> bucket_base (excl), row_ptr[N] -----
__global__ __launch_bounds__(256) void bscan_kernel(const int* __restrict__ bucket_cursor,
                                                    int* __restrict__ bucket_base,
                                                    int* __restrict__ row_ptr,
                                                    int N, int nbuck) {
    __shared__ int sm[256];
    int tid = threadIdx.x;
    int K = (nbuck + 255) / 256;
    int b0 = tid * K;
    int local = 0;
    for (int k = 0; k < K; ++k) {
        int b = b0 + k;
        if (b < nbuck) {
            int nodes = min(128, N - (b << BSH));
            local += bucket_cursor[b] - b * CAP + nodes;
        }
    }
    sm[tid] = local;
    __syncthreads();
    for (int st = 1; st < 256; st <<= 1) {
        int v = sm[tid];
        int a = (tid >= st) ? sm[tid - st] : 0;
        __syncthreads();
        sm[tid] = v + a;
        __syncthreads();
    }
    int run = (tid == 0) ? 0 : sm[tid - 1];
    for (int k = 0; k < K; ++k) {
        int b = b0 + k;
        if (b < nbuck) {
            int nodes = min(128, N - (b << BSH));
            int c = bucket_cursor[b] - b * CAP + nodes;
            bucket_base[b] = run;
            run += c;
        }
    }
    if (tid == 255) {
        bucket_base[nbuck] = sm[255];
        row_ptr[N] = sm[255];
    }
}

// ---- phaseB: per-node count+scan -> row_ptr; synth selfloop; place records --
__global__ __launch_bounds__(256) void phaseB_kernel(const float4* __restrict__ staged,
                                                     const int* __restrict__ bucket_base,
                                                     const int* __restrict__ bucket_cursor,
                                                     const float* __restrict__ easum,
                                                     int* __restrict__ row_ptr,
                                                     float4* __restrict__ recs,
                                                     int N, int E) {
    __shared__ int cnt128[128];
    __shared__ int offs[128];
    int b = blockIdx.x;
    int n0 = b << BSH;
    int tid = threadIdx.x;
    if (tid < 128) cnt128[tid] = 0;
    __syncthreads();
    int sbeg = b * CAP;
    int send = bucket_cursor[b];          // slack run end
    for (int i = sbeg + tid; i < send; i += 256) {
        int d = __float_as_int(staged[i].w);
        atomicAdd(&cnt128[d - n0], 1);
    }
    __syncthreads();
    int node = n0 + tid;
    int tot = 0;
    if (tid < 128) {
        tot = cnt128[tid] + ((node < N) ? 1 : 0);   // +1 selfloop
        offs[tid] = tot;
    }
    __syncthreads();
    for (int st = 1; st < 128; st <<= 1) {
        int v = 0;
        if (tid < 128) {
            v = offs[tid];
            if (tid >= st) v += offs[tid - st];
        }
        __syncthreads();
        if (tid < 128) offs[tid] = v;
        __syncthreads();
    }
    float inv = 1.f / (float)E;
    float m0 = easum[0] * inv, m1 = easum[1] * inv;
    if (tid < 128 && node < N) {
        int excl = bucket_base[b] + offs[tid] - tot;
        row_ptr[node] = excl;
        // selfloop record at the node's first CSR slot
        recs[excl] = make_float4(__int_as_float(node), m0, m1, __int_as_float(node));
        offs[tid] = excl + 1;
    }
    __syncthreads();
    for (int i = sbeg + tid; i < send; i += 256) {
        float4 r = staged[i];
        int d = __float_as_int(r.w);
        int pos = atomicAdd(&offs[d - n0], 1);
        recs[pos] = r;
    }
}

// ---- wgt0: edge-parallel layer-0 attention weights --------------------------
__global__ __launch_bounds__(256) void wgt0_kernel(const float2* __restrict__ x,
                                                   const float* __restrict__ W0,
                                                   const float* __restrict__ b0,
                                                   const float4* __restrict__ recs,
                                                   const float* __restrict__ We,
                                                   const float* __restrict__ att,
                                                   float4* __restrict__ wrec, int EP) {
    int lane = threadIdx.x & 63;
    int m = lane & 15, quad = lane >> 4;
    int c0 = quad * 8, c1 = 32 + c0;
    float w0a[8], w1a[8], ata[8], w0b[8], w1b[8], atb[8];
    float Wxa[8], Wya[8], bca[8], Wxb[8], Wyb[8], bcb[8];
#pragma unroll
    for (int j = 0; j < 8; ++j) {
        w0a[j] = We[c0 + j];  w1a[j] = We[64 + c0 + j];  ata[j] = att[c0 + j];
        w0b[j] = We[c1 + j];  w1b[j] = We[64 + c1 + j];  atb[j] = att[c1 + j];
        Wxa[j] = W0[c0 + j];  Wya[j] = W0[64 + c0 + j];  bca[j] = b0[c0 + j];
        Wxb[j] = W0[c1 + j];  Wyb[j] = W0[64 + c1 + j];  bcb[j] = b0[c1 + j];
    }
    int ntiles = (EP + 15) >> 4;
    int wid = (blockIdx.x * blockDim.x + threadIdx.x) >> 6;
    int nw = (gridDim.x * blockDim.x) >> 6;
    for (int t = wid; t < ntiles; t += nw) {
        int e = t * 16 + m;
        int ec = e < EP ? e : EP - 1;
        float4 r = recs[ec];
        int s = __float_as_int(r.x);
        int d = __float_as_int(r.w);
        float2 xs = x[s];
        float2 xd = x[d];
        float P0 = 0.f, P1 = 0.f;
#pragma unroll
        for (int j = 0; j < 8; ++j) {
            float zs = fmaf(xs.x, Wxa[j], fmaf(xs.y, Wya[j], bca[j]));
            float zd = fmaf(xd.x, Wxa[j], fmaf(xd.y, Wya[j], bca[j]));
            float t0 = zd + zs + fmaf(r.y, w0a[j], r.z * w1a[j]);
            t0 = fmaxf(t0, 0.2f * t0);
            P0 = fmaf(t0, ata[j], P0);
            float zs1 = fmaf(xs.x, Wxb[j], fmaf(xs.y, Wyb[j], bcb[j]));
            float zd1 = fmaf(xd.x, Wxb[j], fmaf(xd.y, Wyb[j], bcb[j]));
            float t1 = zd1 + zs1 + fmaf(r.y, w0b[j], r.z * w1b[j]);
            t1 = fmaxf(t1, 0.2f * t1);
            P1 = fmaf(t1, atb[j], P1);
        }
        P0 += swz<0x401F>(P0);             // quad pair (xor 16)
        P1 += swz<0x401F>(P1);
        P0 += __shfl_xor(P0, 32);          // cross-half (xor 32)
        P1 += __shfl_xor(P1, 32);
        float w0 = __expf(fminf(P0, 60.f));
        float w1 = __expf(fminf(P1, 60.f));
        if (lane < 16 && e < EP) wrec[e] = make_float4(w0, w1, xs.x, xs.y);
    }
}

// ---- hagg0: wave/node, lanes=EDGES; stream wrec; 6-scalar butterfly ---------
__global__ __launch_bounds__(256) void hagg0_kernel(const float4* __restrict__ wrec,
                                                    const int* __restrict__ row_ptr,
                                                    const float* __restrict__ W0,
                                                    const float* __restrict__ b0,
                                                    const float* __restrict__ bias,
                                                    float* __restrict__ hout, int N) {
    int gtid = blockIdx.x * blockDim.x + threadIdx.x;
    int n = gtid >> 6;
    if (n >= N) return;
    n = __builtin_amdgcn_readfirstlane(n);
    int lane = threadIdx.x & 63;
    int beg = row_ptr[n], end = row_ptr[n + 1];
    float a0 = 0.f, a1 = 0.f, a2 = 0.f, c0 = 0.f, c1 = 0.f, c2 = 0.f;
    for (int i = beg + lane; i < end; i += 64) {
        float4 r = wrec[i];
        a0 += r.x; a1 = fmaf(r.x, r.z, a1); a2 = fmaf(r.x, r.w, a2);
        c0 += r.y; c1 = fmaf(r.y, r.z, c1); c2 = fmaf(r.y, r.w, c2);
    }
#pragma unroll
    for (int o = 32; o >= 1; o >>= 1) {
        a0 += __shfl_xor(a0, o); a1 += __shfl_xor(a1, o); a2 += __shfl_xor(a2, o);
        c0 += __shfl_xor(c0, o); c1 += __shfl_xor(c1, o); c2 += __shfl_xor(c2, o);
    }
    int head = lane >> 5;
    float l  = head ? c0 : a0;
    float Sx = head ? c1 : a1;
    float Sy = head ? c2 : a2;
    float num = fmaf(W0[lane], Sx, fmaf(W0[64 + lane], Sy, b0[lane] * l));
    float v = num / (l + 1e-16f) + bias[lane];
    v = (v > 0.f) ? v : expm1f(v);       // ELU
    hout[(size_t)n * 64 + lane] = v;
}

// ---- agg1: fused attention+aggregation, layer 1; z stored FP16 --------------
__global__ __launch_bounds__(256) void agg1_kernel(
    const __half* __restrict__ z, const int* __restrict__ row_ptr,
    const float4* __restrict__ recs,
    const float* __restrict__ We, const float* __restrict__ att,
    const float* __restrict__ bias, float* __restrict__ hout, int N) {
    int gtid = blockIdx.x * blockDim.x + threadIdx.x;
    int n = gtid >> 6;
    if (n >= N) return;
    n = __builtin_amdgcn_readfirstlane(n);
    int lane = threadIdx.x & 63;

    float We0 = We[lane], We1 = We[64 + lane];
    float attj = att[lane];
    float zn = __half2float(z[(size_t)n * 64 + lane]);

    int beg = row_ptr[n], end = row_ptr[n + 1];
    float ll[4] = {0.f, 0.f, 0.f, 0.f};
    float aa[4] = {0.f, 0.f, 0.f, 0.f};
    int i = beg;
    for (; i + 8 <= end; i += 8) {
        float w[8], zs[8];
#pragma unroll
        for (int k = 0; k < 8; ++k) {
            float4 r = recs[i + k];
            int s = __builtin_amdgcn_readfirstlane(__float_as_int(r.x));
            float zv = __half2float(z[(size_t)s * 64 + lane]);
            float sj = zn + zv + fmaf(r.y, We0, r.z * We1);
            sj = fmaxf(sj, 0.2f * sj);
            float alpha = head_reduce(sj * attj);
            w[k] = __expf(fminf(alpha, 60.f));
            zs[k] = zv;
        }
#pragma unroll
        for (int k = 0; k < 8; ++k) {
            ll[k & 3] += w[k];
            aa[k & 3] = fmaf(w[k], zs[k], aa[k & 3]);
        }
    }
    for (; i < end; ++i) {
        float4 r = recs[i];
        int s = __builtin_amdgcn_readfirstlane(__float_as_int(r.x));
        float zv = __half2float(z[(size_t)s * 64 + lane]);
        float sj = zn + zv + fmaf(r.y, We0, r.z * We1);
        sj = fmaxf(sj, 0.2f * sj);
        float alpha = head_reduce(sj * attj);
        float w = __expf(fminf(alpha, 60.f));
        ll[0] += w;
        aa[0] = fmaf(w, zv, aa[0]);
    }
    float l = (ll[0] + ll[1]) + (ll[2] + ll[3]);
    float a = (aa[0] + aa[1]) + (aa[2] + aa[3]);
    float v = a / (l + 1e-16f) + bias[lane];
    v = (v > 0.f) ? v : expm1f(v);
    hout[(size_t)n * 64 + lane] = v;
}

// ---- out[N x 64] = h[N x 64] @ B[64 x 64] (+ bias), split-bf16 MFMA ---------
// FP16 output (consumed by random-gather kernels: halves their HBM traffic).
__global__ __launch_bounds__(256) void mfma_gemm64(const float* __restrict__ h,
                                                   const short* __restrict__ Bf,
                                                   const float* __restrict__ bias,
                                                   __half* __restrict__ out, int N,
                                                   const float* __restrict__ Wm1,
                                                   const float* __restrict__ bm1,
                                                   const int* __restrict__ dest,
                                                   float* __restrict__ gv) {
    int wave = threadIdx.x >> 6;
    int lane = threadIdx.x & 63;
    int n0 = blockIdx.x * 64 + wave * 16;
    if (n0 < N) {
        int m = lane & 15, quad = lane >> 4;
        int arow = n0 + m;
        if (arow > N - 1) arow = N - 1;
        f32x4 acc[4] = {{0.f, 0.f, 0.f, 0.f}, {0.f, 0.f, 0.f, 0.f},
                        {0.f, 0.f, 0.f, 0.f}, {0.f, 0.f, 0.f, 0.f}};
#pragma unroll
        for (int s = 0; s < 2; ++s) {
            const float* ap = h + (size_t)arow * 64 + s * 32 + quad * 8;
            float4 a0 = *(const float4*)ap;
            float4 a1 = *(const float4*)(ap + 4);
            short8 ahi, alo;
            short2 t;
            t = bsplit(a0.x); ahi[0] = t.x; alo[0] = t.y;
            t = bsplit(a0.y); ahi[1] = t.x; alo[1] = t.y;
            t = bsplit(a0.z); ahi[2] = t.x; alo[2] = t.y;
            t = bsplit(a0.w); ahi[3] = t.x; alo[3] = t.y;
            t = bsplit(a1.x); ahi[4] = t.x; alo[4] = t.y;
            t = bsplit(a1.y); ahi[5] = t.x; alo[5] = t.y;
            t = bsplit(a1.z); ahi[6] = t.x; alo[6] = t.y;
            t = bsplit(a1.w); ahi[7] = t.x; alo[7] = t.y;
#pragma unroll
            for (int nt = 0; nt < 4; ++nt) {
                const short* bp = Bf + ((s * 4 + nt) * 2) * 512 + lane * 8;
                short8 bhi = *(const short8*)bp;
                short8 blo = *(const short8*)(bp + 512);
                acc[nt] = __builtin_amdgcn_mfma_f32_16x16x32_bf16(ahi, bhi, acc[nt], 0, 0, 0);
                acc[nt] = __builtin_amdgcn_mfma_f32_16x16x32_bf16(ahi, blo, acc[nt], 0, 0, 0);
                acc[nt] = __builtin_amdgcn_mfma_f32_16x16x32_bf16(alo, bhi, acc[nt], 0, 0, 0);
            }
        }
#pragma unroll
        for (int nt = 0; nt < 4; ++nt) {
            int col = nt * 16 + m;
            float bj = bias ? bias[col] : 0.f;
#pragma unroll
            for (int r = 0; r < 4; ++r) {
                int orow = n0 + quad * 4 + r;
                if (orow < N) out[(size_t)orow * 64 + col] = __float2half(acc[nt][r] + bj);
            }
        }
    }
    if (gv && blockIdx.x == 0 && threadIdx.x < 32) {
        int dd = dest[0];
        int q = threadIdx.x;
        float acc2 = bm1[q];
        for (int k = 0; k < 64; ++k)
            acc2 = fmaf(h[(size_t)dd * 64 + k], Wm1[(128 + k) * 32 + q], acc2);
        gv[q] = acc2;
    }
}

// 8 lanes per edge; hsd FP16: [n*64+0:32]=hs, [n*64+32:64]=hd
__global__ __launch_bounds__(256) void edge_mlp_kernel(
    const int* __restrict__ ei, const float2* __restrict__ ea,
    const __half* __restrict__ hsd, const float* __restrict__ gvec,
    const float* __restrict__ WrowA, const float* __restrict__ WrowB,
    const float* __restrict__ Wm2, const float* __restrict__ bm2,
    float* __restrict__ out, int E) {
    int tid = blockIdx.x * blockDim.x + threadIdx.x;
    int e = tid >> 3;
    int j = tid & 7;
    if (e >= E) return;
    int s = ei[e], d = ei[E + e];
    float2 eav = ea[e];
    const __half2* ps = (const __half2*)(hsd + (size_t)s * 64 + j * 4);
    const __half2* pd = (const __half2*)(hsd + (size_t)d * 64 + 32 + j * 4);
    float2 a01 = __half22float2(ps[0]), a23 = __half22float2(ps[1]);
    float2 b01 = __half22float2(pd[0]), b23 = __half22float2(pd[1]);
    float4 g = *(const float4*)(gvec + j * 4);
    float4 wa = *(const float4*)(WrowA + j * 4);
    float4 wb = *(const float4*)(WrowB + j * 4);
    float4 w2 = *(const float4*)(Wm2 + j * 4);
    float acc = 0.f, v;
    v = fmaf(eav.x, wa.x, fmaf(eav.y, wb.x, a01.x + b01.x + g.x)); v = fmaxf(v, 0.f); acc = fmaf(v, w2.x, acc);
    v = fmaf(eav.x, wa.y, fmaf(eav.y, wb.y, a01.y + b01.y + g.y)); v = fmaxf(v, 0.f); acc = fmaf(v, w2.y, acc);
    v = fmaf(eav.x, wa.z, fmaf(eav.y, wb.z, a23.x + b23.x + g.z)); v = fmaxf(v, 0.f); acc = fmaf(v, w2.z, acc);
    v = fmaf(eav.x, wa.w, fmaf(eav.y, wb.w, a23.y + b23.y + g.w)); v = fmaxf(v, 0.f); acc = fmaf(v, w2.w, acc);
    acc = dpp_add<0xB1>(acc);    // xor 1
    acc = dpp_add<0x4E>(acc);    // xor 2
    acc = dpp_add<0x141>(acc);   // xor 7 — closes the 8-group
    if (j == 0) out[e] = acc + bm2[0];
}

extern "C" void kernel_launch(void* const* d_in, const int* in_sizes, int n_in,
                              void* d_out, int out_size, void* d_ws, size_t ws_size,
                              hipStream_t stream) {
    const float* x     = (const float*)d_in[0];
    const int*   ei    = (const int*)d_in[1];
    const float* ea    = (const float*)d_in[2];
    const int*   dest  = (const int*)d_in[3];
    const float* W0    = (const float*)d_in[4];
    const float* b0    = (const float*)d_in[5];
    const float* We0   = (const float*)d_in[6];
    const float* att0  = (const float*)d_in[7];
    const float* bias0 = (const float*)d_in[8];
    const float* W1    = (const float*)d_in[9];
    const float* b1    = (const float*)d_in[10];
    const float* We1   = (const float*)d_in[11];
    const float* att1  = (const float*)d_in[12];
    const float* bias1 = (const float*)d_in[13];
    const float* Wm1   = (const float*)d_in[14];
    const float* bm1   = (const float*)d_in[15];
    const float* Wm2   = (const float*)d_in[16];
    const float* bm2   = (const float*)d_in[17];

    const int N = in_sizes[0] / 2;
    const int E = in_sizes[1] / 2;
    const int EP = E + N;
    const int nbuck = (N + 127) >> BSH;
    const int nchunk = (E + CH - 1) / CH;

    char* ws = (char*)d_ws;
    size_t off = 0;
    auto alloc = [&](size_t bytes) -> void* {
        void* p = ws + off;
        off += bytes;
        off = (off + 255) & ~(size_t)255;
        return p;
    };
    int*    bucket_base   = (int*)alloc((size_t)(nbuck + 1) * 4);
    int*    bucket_cursor = (int*)alloc((size_t)nbuck * 4);
    int*    row_ptr       = (int*)alloc((size_t)(N + 1) * 4);
    size_t  slack_bytes   = (size_t)nbuck * CAP * 16;
    size_t  shared_bytes  = slack_bytes > (size_t)N * 128 ? slack_bytes : (size_t)N * 128;
    float4* staged        = (float4*)alloc(shared_bytes);   // also z16/hsd16 (N*64*2B)
    float4* recs          = (float4*)alloc((size_t)EP * 16);
    float4* wrec          = (float4*)alloc((size_t)EP * 16);
    float*  hbuf          = (float*)alloc((size_t)N * 64 * 4);
    float*  easum         = (float*)alloc(8);
    float*  gvec          = (float*)alloc(32 * 4);
    short*  BfW1          = (short*)alloc(8192 * 2);
    short*  BfWm          = (short*)alloc(8192 * 2);
    __half* z16           = (__half*)staged;  // staged dead before gemm writes
    __half* hsd16         = z16;              // z1 dead after layer-1 agg

    dim3 blk(256);
    setup_kernel<<<3, 512, 0, stream>>>(W1, Wm1, BfW1, BfWm, bucket_cursor, easum, nbuck);
    phaseA_kernel<<<nchunk, blk, (size_t)nbuck * 8, stream>>>(ei, (const float2*)ea,
                                                              bucket_cursor, easum,
                                                              staged, E, nbuck);
    bscan_kernel<<<1, blk, 0, stream>>>(bucket_cursor, bucket_base, row_ptr, N, nbuck);
    phaseB_kernel<<<nbuck, blk, 0, stream>>>(staged, bucket_base, bucket_cursor, easum,
                                             row_ptr, recs, N, E);
    wgt0_kernel<<<2048, blk, 0, stream>>>((const float2*)x, W0, b0, recs, We0, att0, wrec, EP);
    hagg0_kernel<<<(N * 64 + 255) / 256, blk, 0, stream>>>(wrec, row_ptr, W0, b0,
                                                           bias0, hbuf, N);
    mfma_gemm64<<<(N + 63) / 64, blk, 0, stream>>>(hbuf, BfW1, b1, z16, N,
                                                   nullptr, nullptr, nullptr, nullptr);
    agg1_kernel<<<(N * 64 + 255) / 256, blk, 0, stream>>>(z16, row_ptr, recs,
                                                          We1, att1, bias1, hbuf, N);
    mfma_gemm64<<<(N + 63) / 64, blk, 0, stream>>>(hbuf, BfWm, (const float*)nullptr, hsd16, N,
                                                   Wm1, bm1, dest, gvec);
    edge_mlp_kernel<<<((size_t)E * 8 + 255) / 256, blk, 0, stream>>>(
        ei, (const float2*)ea, hsd16, gvec,
        Wm1 + 192 * 32, Wm1 + 193 * 32, Wm2, bm2, (float*)d_out, E);
}